// Round 1
// baseline (422.115 us; speedup 1.0000x reference)
//
#include <hip/hip_runtime.h>
#include <math.h>

// EquiAttention, MI355X. Single-pass streaming over messages (256 MB), fused
// masked-softmax + weighted-sum + L2-norm scaling + output projection.
// Kernel 1 precomputes proj_equi = v_equi @ w_coord^T into d_ws.

namespace {

constexpr int kB   = 4;
constexpr int kNQ  = 512;
constexpr int kNKV = 512;
constexpr int kD   = 64;
constexpr int kQT  = 2;          // q rows per block (amortizes proj reads)
constexpr float kNegInf = -1e10f;

// proj[b,k,c,e] = sum_d v[b,k,c,d] * w[e,d].  4 rows of 64 per block.
__global__ __launch_bounds__(256)
void proj_kernel(const float* __restrict__ v, const float* __restrict__ w,
                 float* __restrict__ out) {
  __shared__ float wt[64 * 65];   // wt[d*65+e] = w[e*64+d]  (+1 pad: no conflicts)
  __shared__ float rows[256];
  const int t = threadIdx.x;
  for (int i = t; i < 4096; i += 256) {
    wt[(i & 63) * 65 + (i >> 6)] = w[i];
  }
  const long rowbase = (long)blockIdx.x * 4;
  rows[t] = v[rowbase * 64 + t];
  __syncthreads();
  const int r = t >> 6;           // wave id == row id -> rows[] reads broadcast
  const int e = t & 63;
  float acc = 0.f;
#pragma unroll
  for (int d = 0; d < 64; ++d) {
    acc = fmaf(rows[r * 64 + d], wt[d * 65 + e], acc);
  }
  out[rowbase * 64 + t] = acc;
}

// One block = (b, q0..q0+1). Wave w handles k in [128w, 128w+128); lane layout:
// ksub = lane>>4 (k offset), d0 = (lane&15)*4 (float4 over d) -> each wave's
// message load is 1 KB contiguous (4 consecutive k-rows).
__global__ __launch_bounds__(256)
void attn_kernel(const float* __restrict__ msg, const int* __restrict__ adj,
                 const float* __restrict__ proj, const float* __restrict__ wattn,
                 float* __restrict__ out) {
  __shared__ float wt[64 * 65];        // w_attn transposed + pad
  __shared__ float bias[kQT * kNKV];   // 0 or -1e10 per (q,k)
  __shared__ float red[4][kQT][64][5]; // per-wave partials: S, SQ, A0, A1, A2
  __shared__ float afin[kQT][3][64];   // attn_out * weights, pre-projection

  const int t   = threadIdx.x;
  const int blk = blockIdx.x;
  const int b   = blk / (kNQ / kQT);
  const int q0  = (blk % (kNQ / kQT)) * kQT;

  for (int i = t; i < 4096; i += 256) {
    wt[(i & 63) * 65 + (i >> 6)] = wattn[i];
  }
  for (int i = t; i < kQT * kNKV; i += 256) {
    const int q = i >> 9;   // kQT == 2
    const int k = i & (kNKV - 1);
    bias[i] = (adj[((long)(b * kNQ + q0 + q)) * kNKV + k] > 0) ? 0.f : kNegInf;
  }
  __syncthreads();

  const int wave = t >> 6;
  const int lane = t & 63;
  const int ksub = lane >> 4;
  const int d0   = (lane & 15) << 2;

  const float* msg0  = msg + ((long)(b * kNQ + q0)) * kNKV * kD;
  const float* projb = proj + (long)b * kNKV * 3 * kD;

  float s[kQT][4]  = {};
  float sq[kQT][4] = {};
  float a0[kQT][4] = {};
  float a1[kQT][4] = {};
  float a2[kQT][4] = {};

#pragma unroll 4
  for (int it = 0; it < 32; ++it) {
    const int k = wave * 128 + it * 4 + ksub;
    const float4 p0 = *(const float4*)(projb + ((long)k * 3 + 0) * kD + d0);
    const float4 p1 = *(const float4*)(projb + ((long)k * 3 + 1) * kD + d0);
    const float4 p2 = *(const float4*)(projb + ((long)k * 3 + 2) * kD + d0);
#pragma unroll
    for (int j = 0; j < kQT; ++j) {
      const float4 m = *(const float4*)(msg0 + ((long)j * kNKV + k) * kD + d0);
      const float bj = bias[j * kNKV + k];
      const float e0 = __expf(m.x + bj);   // masked: exp(-1e10) underflows to 0
      const float e1 = __expf(m.y + bj);
      const float e2 = __expf(m.z + bj);
      const float e3 = __expf(m.w + bj);
      s[j][0] += e0; s[j][1] += e1; s[j][2] += e2; s[j][3] += e3;
      sq[j][0] = fmaf(e0, e0, sq[j][0]);
      sq[j][1] = fmaf(e1, e1, sq[j][1]);
      sq[j][2] = fmaf(e2, e2, sq[j][2]);
      sq[j][3] = fmaf(e3, e3, sq[j][3]);
      a0[j][0] = fmaf(e0, p0.x, a0[j][0]);
      a0[j][1] = fmaf(e1, p0.y, a0[j][1]);
      a0[j][2] = fmaf(e2, p0.z, a0[j][2]);
      a0[j][3] = fmaf(e3, p0.w, a0[j][3]);
      a1[j][0] = fmaf(e0, p1.x, a1[j][0]);
      a1[j][1] = fmaf(e1, p1.y, a1[j][1]);
      a1[j][2] = fmaf(e2, p1.z, a1[j][2]);
      a1[j][3] = fmaf(e3, p1.w, a1[j][3]);
      a2[j][0] = fmaf(e0, p2.x, a2[j][0]);
      a2[j][1] = fmaf(e1, p2.y, a2[j][1]);
      a2[j][2] = fmaf(e2, p2.z, a2[j][2]);
      a2[j][3] = fmaf(e3, p2.w, a2[j][3]);
    }
  }

  // Reduce across the 4 k-subgroups within the wave (lanes xor 16, xor 32).
#pragma unroll
  for (int j = 0; j < kQT; ++j) {
#pragma unroll
    for (int i = 0; i < 4; ++i) {
      s[j][i]  += __shfl_xor(s[j][i], 16, 64);
      s[j][i]  += __shfl_xor(s[j][i], 32, 64);
      sq[j][i] += __shfl_xor(sq[j][i], 16, 64);
      sq[j][i] += __shfl_xor(sq[j][i], 32, 64);
      a0[j][i] += __shfl_xor(a0[j][i], 16, 64);
      a0[j][i] += __shfl_xor(a0[j][i], 32, 64);
      a1[j][i] += __shfl_xor(a1[j][i], 16, 64);
      a1[j][i] += __shfl_xor(a1[j][i], 32, 64);
      a2[j][i] += __shfl_xor(a2[j][i], 16, 64);
      a2[j][i] += __shfl_xor(a2[j][i], 32, 64);
    }
  }
  if (lane < 16) {
#pragma unroll
    for (int j = 0; j < kQT; ++j) {
#pragma unroll
      for (int i = 0; i < 4; ++i) {
        const int d = d0 + i;
        red[wave][j][d][0] = s[j][i];
        red[wave][j][d][1] = sq[j][i];
        red[wave][j][d][2] = a0[j][i];
        red[wave][j][d][3] = a1[j][i];
        red[wave][j][d][4] = a2[j][i];
      }
    }
  }
  __syncthreads();

  // Cross-wave reduce + fold normalization and L2-norm weight:
  // attn_out*weights = A_c * sqrt(SQ) / S^2
  if (t < kQT * 64) {
    const int q = t >> 6;
    const int d = t & 63;
    float S = 0.f, SQ = 0.f, A0 = 0.f, A1 = 0.f, A2 = 0.f;
#pragma unroll
    for (int w = 0; w < 4; ++w) {
      S  += red[w][q][d][0];
      SQ += red[w][q][d][1];
      A0 += red[w][q][d][2];
      A1 += red[w][q][d][3];
      A2 += red[w][q][d][4];
    }
    const float inv = 1.f / S;
    const float wgt = sqrtf(SQ) * inv * inv;
    afin[q][0][d] = A0 * wgt;
    afin[q][1][d] = A1 * wgt;
    afin[q][2][d] = A2 * wgt;
  }
  __syncthreads();

  // out[b,q,c,e] = sum_d afin[q][c][d] * w_attn[e][d]
  for (int o = t; o < kQT * 3 * 64; o += 256) {
    const int q = o / 192;
    const int c = (o % 192) / 64;
    const int e = o & 63;
    float acc = 0.f;
#pragma unroll
    for (int d = 0; d < 64; ++d) {
      acc = fmaf(afin[q][c][d], wt[d * 65 + e], acc);
    }
    out[(((long)(b * kNQ + q0 + q)) * 3 + c) * kD + e] = acc;
  }
}

}  // namespace

extern "C" void kernel_launch(void* const* d_in, const int* in_sizes, int n_in,
                              void* d_out, int out_size, void* d_ws, size_t ws_size,
                              hipStream_t stream) {
  const float* v_equi   = (const float*)d_in[0];
  const float* messages = (const float*)d_in[1];
  const int*   adj      = (const int*)d_in[2];
  const float* w_coord  = (const float*)d_in[3];
  const float* w_attn   = (const float*)d_in[4];
  float* outp = (float*)d_out;
  float* projw = (float*)d_ws;  // B*NKV*3*D floats = 1.5 MB

  proj_kernel<<<kB * kNKV * 3 / 4, 256, 0, stream>>>(v_equi, w_coord, projw);
  attn_kernel<<<kB * (kNQ / kQT), 256, 0, stream>>>(messages, adj, projw, w_attn, outp);
}

// Round 2
// 378.027 us; speedup vs baseline: 1.1166x; 1.1166x over previous
//
#include <hip/hip_runtime.h>
#include <math.h>

// EquiAttention, MI355X. Single-pass streaming over messages (256 MB), fused
// masked-softmax + weighted-sum + L2-norm scaling + output projection.
// R2: explicit double-buffered register pipeline in the k-loop so the 5
// global loads per step are issued a full body ahead (R1 was latency-bound:
// VGPR=72 => compiler serialized loads; all pipes <12% busy).

namespace {

constexpr int kB   = 4;
constexpr int kNQ  = 512;
constexpr int kNKV = 512;
constexpr int kD   = 64;
constexpr int kQT  = 2;          // q rows per block
constexpr float kNegInf = -1e10f;

// proj[b,k,c,e] = sum_d v[b,k,c,d] * w[e,d].  4 rows of 64 per block.
__global__ __launch_bounds__(256)
void proj_kernel(const float* __restrict__ v, const float* __restrict__ w,
                 float* __restrict__ out) {
  __shared__ float wt[64 * 65];   // wt[d*65+e] = w[e*64+d]  (+1 pad)
  __shared__ float rows[256];
  const int t = threadIdx.x;
  for (int i = t; i < 4096; i += 256) {
    wt[(i & 63) * 65 + (i >> 6)] = w[i];
  }
  const long rowbase = (long)blockIdx.x * 4;
  rows[t] = v[rowbase * 64 + t];
  __syncthreads();
  const int r = t >> 6;
  const int e = t & 63;
  float acc = 0.f;
#pragma unroll
  for (int d = 0; d < 64; ++d) {
    acc = fmaf(rows[r * 64 + d], wt[d * 65 + e], acc);
  }
  out[rowbase * 64 + t] = acc;
}

struct Stage {
  float4 m0, m1;      // messages for q0, q0+1 (4 d-values each)
  float4 p0, p1, p2;  // proj_equi c=0,1,2
  float  b0, b1;      // mask bias per q (from LDS)
};

__device__ __forceinline__ void issue(Stage& S,
    const float* __restrict__ mp0, const float* __restrict__ mp1,
    const float* __restrict__ pp,
    const float* bp0, const float* bp1, int it) {
  const int mo = it * 4 * kD;        // msg advances 4 rows of 64 per step
  const int po = it * 4 * 3 * kD;    // proj advances 4 rows of 3*64 per step
  S.p0 = *(const float4*)(pp + po);
  S.p1 = *(const float4*)(pp + po + kD);
  S.p2 = *(const float4*)(pp + po + 2 * kD);
  S.m0 = *(const float4*)(mp0 + mo);
  S.m1 = *(const float4*)(mp1 + mo);
  S.b0 = bp0[it * 4];
  S.b1 = bp1[it * 4];
}

// One block = (b, q0..q0+1). Wave w owns k in [128w,128w+128); lane layout:
// ksub = lane>>4, d0 = (lane&15)*4 -> each wave msg load = 1 KB contiguous.
__global__ __launch_bounds__(256, 4)
void attn_kernel(const float* __restrict__ msg, const int* __restrict__ adj,
                 const float* __restrict__ proj, const float* __restrict__ wattn,
                 float* __restrict__ out) {
  __shared__ float wt[64 * 65];        // w_attn transposed + pad
  __shared__ float bias[kQT * kNKV];   // 0 or -1e10 per (q,k)
  __shared__ float red[4][kQT][64][5]; // per-wave partials: S, SQ, A0, A1, A2
  __shared__ float afin[kQT][3][64];   // attn_out * weights, pre-projection

  const int t   = threadIdx.x;
  const int blk = blockIdx.x;
  const int b   = blk / (kNQ / kQT);
  const int q0  = (blk % (kNQ / kQT)) * kQT;

  for (int i = t; i < 4096; i += 256) {
    wt[(i & 63) * 65 + (i >> 6)] = wattn[i];
  }
  for (int i = t; i < kQT * kNKV; i += 256) {
    const int q = i >> 9;   // kQT == 2
    const int k = i & (kNKV - 1);
    bias[i] = (adj[((long)(b * kNQ + q0 + q)) * kNKV + k] > 0) ? 0.f : kNegInf;
  }
  __syncthreads();

  const int wave = t >> 6;
  const int lane = t & 63;
  const int ksub = lane >> 4;
  const int d0   = (lane & 15) << 2;
  const int wbase = wave * 128;

  const float* mp0 = msg + ((long)(b * kNQ + q0) * kNKV + wbase + ksub) * kD + d0;
  const float* mp1 = mp0 + (long)kNKV * kD;
  const float* pp  = proj + ((long)b * kNKV + wbase + ksub) * 3 * kD + d0;
  const float* bp0 = &bias[wbase + ksub];
  const float* bp1 = &bias[kNKV + wbase + ksub];

  float s[kQT][4]  = {};
  float sq[kQT][4] = {};
  float a0[kQT][4] = {};
  float a1[kQT][4] = {};
  float a2[kQT][4] = {};

  auto consume = [&](const Stage& S) {
    const float e00 = __expf(S.m0.x + S.b0);
    const float e01 = __expf(S.m0.y + S.b0);
    const float e02 = __expf(S.m0.z + S.b0);
    const float e03 = __expf(S.m0.w + S.b0);
    const float e10 = __expf(S.m1.x + S.b1);
    const float e11 = __expf(S.m1.y + S.b1);
    const float e12 = __expf(S.m1.z + S.b1);
    const float e13 = __expf(S.m1.w + S.b1);
    s[0][0] += e00; s[0][1] += e01; s[0][2] += e02; s[0][3] += e03;
    s[1][0] += e10; s[1][1] += e11; s[1][2] += e12; s[1][3] += e13;
    sq[0][0] = fmaf(e00, e00, sq[0][0]);
    sq[0][1] = fmaf(e01, e01, sq[0][1]);
    sq[0][2] = fmaf(e02, e02, sq[0][2]);
    sq[0][3] = fmaf(e03, e03, sq[0][3]);
    sq[1][0] = fmaf(e10, e10, sq[1][0]);
    sq[1][1] = fmaf(e11, e11, sq[1][1]);
    sq[1][2] = fmaf(e12, e12, sq[1][2]);
    sq[1][3] = fmaf(e13, e13, sq[1][3]);
    a0[0][0] = fmaf(e00, S.p0.x, a0[0][0]);
    a0[0][1] = fmaf(e01, S.p0.y, a0[0][1]);
    a0[0][2] = fmaf(e02, S.p0.z, a0[0][2]);
    a0[0][3] = fmaf(e03, S.p0.w, a0[0][3]);
    a0[1][0] = fmaf(e10, S.p0.x, a0[1][0]);
    a0[1][1] = fmaf(e11, S.p0.y, a0[1][1]);
    a0[1][2] = fmaf(e12, S.p0.z, a0[1][2]);
    a0[1][3] = fmaf(e13, S.p0.w, a0[1][3]);
    a1[0][0] = fmaf(e00, S.p1.x, a1[0][0]);
    a1[0][1] = fmaf(e01, S.p1.y, a1[0][1]);
    a1[0][2] = fmaf(e02, S.p1.z, a1[0][2]);
    a1[0][3] = fmaf(e03, S.p1.w, a1[0][3]);
    a1[1][0] = fmaf(e10, S.p1.x, a1[1][0]);
    a1[1][1] = fmaf(e11, S.p1.y, a1[1][1]);
    a1[1][2] = fmaf(e12, S.p1.z, a1[1][2]);
    a1[1][3] = fmaf(e13, S.p1.w, a1[1][3]);
    a2[0][0] = fmaf(e00, S.p2.x, a2[0][0]);
    a2[0][1] = fmaf(e01, S.p2.y, a2[0][1]);
    a2[0][2] = fmaf(e02, S.p2.z, a2[0][2]);
    a2[0][3] = fmaf(e03, S.p2.w, a2[0][3]);
    a2[1][0] = fmaf(e10, S.p2.x, a2[1][0]);
    a2[1][1] = fmaf(e11, S.p2.y, a2[1][1]);
    a2[1][2] = fmaf(e12, S.p2.z, a2[1][2]);
    a2[1][3] = fmaf(e13, S.p2.w, a2[1][3]);
  };

  // Software pipeline, distance 1: loads for step it+1 are in flight while
  // computing step it. 32 steps of 4 k-rows each.
  Stage SA, SB;
  issue(SA, mp0, mp1, pp, bp0, bp1, 0);
  for (int it = 0; it < 32; it += 2) {
    issue(SB, mp0, mp1, pp, bp0, bp1, it + 1);
    consume(SA);
    if (it + 2 < 32) issue(SA, mp0, mp1, pp, bp0, bp1, it + 2);
    consume(SB);
  }

  // Reduce across the 4 k-subgroups within the wave (lanes xor 16, xor 32).
#pragma unroll
  for (int j = 0; j < kQT; ++j) {
#pragma unroll
    for (int i = 0; i < 4; ++i) {
      s[j][i]  += __shfl_xor(s[j][i], 16, 64);
      s[j][i]  += __shfl_xor(s[j][i], 32, 64);
      sq[j][i] += __shfl_xor(sq[j][i], 16, 64);
      sq[j][i] += __shfl_xor(sq[j][i], 32, 64);
      a0[j][i] += __shfl_xor(a0[j][i], 16, 64);
      a0[j][i] += __shfl_xor(a0[j][i], 32, 64);
      a1[j][i] += __shfl_xor(a1[j][i], 16, 64);
      a1[j][i] += __shfl_xor(a1[j][i], 32, 64);
      a2[j][i] += __shfl_xor(a2[j][i], 16, 64);
      a2[j][i] += __shfl_xor(a2[j][i], 32, 64);
    }
  }
  if (lane < 16) {
#pragma unroll
    for (int j = 0; j < kQT; ++j) {
#pragma unroll
      for (int i = 0; i < 4; ++i) {
        const int d = d0 + i;
        red[wave][j][d][0] = s[j][i];
        red[wave][j][d][1] = sq[j][i];
        red[wave][j][d][2] = a0[j][i];
        red[wave][j][d][3] = a1[j][i];
        red[wave][j][d][4] = a2[j][i];
      }
    }
  }
  __syncthreads();

  // Cross-wave reduce + fold normalization and L2-norm weight:
  // attn_out*weights = A_c * sqrt(SQ) / S^2
  if (t < kQT * 64) {
    const int q = t >> 6;
    const int d = t & 63;
    float S = 0.f, SQ = 0.f, A0 = 0.f, A1 = 0.f, A2 = 0.f;
#pragma unroll
    for (int w = 0; w < 4; ++w) {
      S  += red[w][q][d][0];
      SQ += red[w][q][d][1];
      A0 += red[w][q][d][2];
      A1 += red[w][q][d][3];
      A2 += red[w][q][d][4];
    }
    const float inv = 1.f / S;
    const float wgt = sqrtf(SQ) * inv * inv;
    afin[q][0][d] = A0 * wgt;
    afin[q][1][d] = A1 * wgt;
    afin[q][2][d] = A2 * wgt;
  }
  __syncthreads();

  // out[b,q,c,e] = sum_d afin[q][c][d] * w_attn[e][d]
  for (int o = t; o < kQT * 3 * 64; o += 256) {
    const int q = o / 192;
    const int c = (o % 192) / 64;
    const int e = o & 63;
    float acc = 0.f;
#pragma unroll
    for (int d = 0; d < 64; ++d) {
      acc = fmaf(afin[q][c][d], wt[d * 65 + e], acc);
    }
    out[(((long)(b * kNQ + q0 + q)) * 3 + c) * kD + e] = acc;
  }
}

}  // namespace

extern "C" void kernel_launch(void* const* d_in, const int* in_sizes, int n_in,
                              void* d_out, int out_size, void* d_ws, size_t ws_size,
                              hipStream_t stream) {
  const float* v_equi   = (const float*)d_in[0];
  const float* messages = (const float*)d_in[1];
  const int*   adj      = (const int*)d_in[2];
  const float* w_coord  = (const float*)d_in[3];
  const float* w_attn   = (const float*)d_in[4];
  float* outp = (float*)d_out;
  float* projw = (float*)d_ws;  // B*NKV*3*D floats = 1.5 MB

  proj_kernel<<<kB * kNKV * 3 / 4, 256, 0, stream>>>(v_equi, w_coord, projw);
  attn_kernel<<<kB * (kNQ / kQT), 256, 0, stream>>>(messages, adj, projw, w_attn, outp);
}